// Round 2
// baseline (8285.695 us; speedup 1.0000x reference)
//
#include <hip/hip_runtime.h>

// LSTM T=16384, B=32, H=96. R14 = 6280us, R15 (chain-fold) = 6240us -- the
// -0.6% vs predicted -5-9% shows the serial chain is NOT the limiter. Model
// refit: per-step ~915cy = ~280cy issue (2 waves sharing a SIMD) + ~600cy
// stall (post-barrier ds_read latency ~120cy, ~13-deep act->c->tanh tail,
// barrier jitter) -- all waves stall in lockstep, SIMDs idle together.
// R16 (this): TWO batch elements per block. 16 blocks x 768 thr (12 waves =
// 3/SIMD, also fixes the 2:2:1:1 SIMD imbalance of 6 waves). NS halved to 256
// so two hist buffers fit LDS (~109 KB). Both halves share the per-step
// barrier; one half's chain/latency stalls are filled by the other half's
// dot issue. Everything inside step() unchanged from R15: XOR-indexed
// pre-scaled weights, gx-folded acc[0], scaled-domain c, v_dot2_f32_f16,
// quad XOR butterfly, one barrier/step, bulk fc flush per window.

constexpr int HH   = 96;
constexpr int BB   = 32;     // total batch
constexpr int TT   = 16384;
constexpr int THH  = 384;    // threads per batch-half
constexpr int TH   = 768;    // 12 waves, 3 per SIMD
constexpr int NB   = 16;     // blocks (2 batches each)
constexpr int NS   = 256;    // h history window (halved: 2 hists in LDS)
constexpr int ROWP = 104;    // halves per hist row: 208 B, 16B-aligned

typedef _Float16 f16x2 __attribute__((ext_vector_type(2)));

__device__ __forceinline__ float dot2_f16(f16x2 a, f16x2 b, float c) {
    float d;
    int ai = __builtin_bit_cast(int, a);
    int bi = __builtin_bit_cast(int, b);
    asm("v_dot2_f32_f16 %0, %1, %2, %3" : "=v"(d) : "v"(ai), "v"(bi), "v"(c));
    return d;
}

template <int CTRL>
__device__ __forceinline__ float dpp_add2(float a, float b) {
    int r = __builtin_amdgcn_mov_dpp(__builtin_bit_cast(int, b), CTRL, 0xF, 0xF, true);
    return a + __builtin_bit_cast(float, r);
}
template <int CTRL>
__device__ __forceinline__ float dpp_bcast(float v) {
    int r = __builtin_amdgcn_mov_dpp(__builtin_bit_cast(int, v), CTRL, 0xF, 0xF, true);
    return __builtin_bit_cast(float, r);
}
constexpr int DPP_XOR1 = 0xB1;  // quad_perm [1,0,3,2]
constexpr int DPP_XOR2 = 0x4E;  // quad_perm [2,3,0,1]
constexpr int DPP_B1   = 0x55;
constexpr int DPP_B2   = 0xAA;
constexpr int DPP_B3   = 0xFF;

#define LOG2E 1.44269504f

__attribute__((amdgpu_flat_work_group_size(TH, TH)))
__global__ void lstm_kernel(const float* __restrict__ x,
                            const float* __restrict__ w_ih,
                            const float* __restrict__ w_hh,
                            const float* __restrict__ b_ih,
                            const float* __restrict__ b_hh,
                            const float* __restrict__ fc_w,
                            const float* __restrict__ fc_b,
                            float* __restrict__ out) {
    __shared__ __align__(16) _Float16 hist[2][(NS + 1) * ROWP];  // 2x ~53.5 KB
    __shared__ __align__(16) float xs[2][NS];                    // 2x 1 KB
    __shared__ float fcw_s[HH];

    const int tid  = threadIdx.x;
    const int half = (tid >= THH) ? 1 : 0;   // which batch of this block
    const int stid = tid - half * THH;
    const int b    = blockIdx.x * 2 + half;  // global batch index
    const int j    = stid >> 2;              // cell 0..95
    const int s    = stid & 3;               // k-slice; also "my gate"

    _Float16* __restrict__ histh = hist[half];
    float*    __restrict__ xsh   = xs[half];

    // XOR-indexed weight layout: slot d holds gate (s^d)'s row slice,
    // PRE-SCALED by e_k(gate) so exp2 consumes the dot output directly.
    f16x2 W[4][12];
#pragma unroll
    for (int d = 0; d < 4; ++d) {
        const int gate = s ^ d;
        const float ek = (gate == 2) ? (-2.0f * LOG2E) : (-LOG2E);
        const float* wr = w_hh + ((gate * HH) + j) * HH + 24 * s;
#pragma unroll
        for (int m = 0; m < 12; ++m)
            W[d][m] = f16x2{(_Float16)(wr[2 * m] * ek), (_Float16)(wr[2 * m + 1] * ek)};
    }
#pragma unroll
    for (int d = 0; d < 4; ++d)
#pragma unroll
        for (int m = 0; m < 12; ++m) asm volatile("" : "+v"(W[d][m]));

    const float ek_s  = (s == 2) ? (-2.0f * LOG2E) : (-LOG2E);
    const float wih2  = w_ih[s * HH + j] * ek_s;
    const float bias2 = (b_ih[s * HH + j] + b_hh[s * HH + j]) * ek_s;
    const float a_mul = (s == 2) ? (-4.0f * LOG2E) : 1.0f;
    const float a_add = (s == 2) ? (2.0f * LOG2E) : 0.0f;

    const float fcb = fc_b[0];
    float c = 0.0f;   // scaled domain: c' = -2*log2e * c_true

    for (int i = tid; i < HH; i += TH) fcw_s[i] = fc_w[i];

    // Bulk fc projection for window [t0, t0+NS): h(t0+i) is in hist row i+1.
    auto flush = [&](int t0) {
        for (int i = stid; i < NS; i += THH) {
            const uint2* hr = (const uint2*)(histh + (i + 1) * ROWP);
            float a = 0.0f;
#pragma unroll
            for (int m = 0; m < 24; ++m) {
                uint2 u = hr[m];
                f16x2 p0 = __builtin_bit_cast(f16x2, u.x);
                f16x2 p1 = __builtin_bit_cast(f16x2, u.y);
                a = fmaf((float)p0.x, fcw_s[4 * m + 0], a);
                a = fmaf((float)p0.y, fcw_s[4 * m + 1], a);
                a = fmaf((float)p1.x, fcw_s[4 * m + 2], a);
                a = fmaf((float)p1.y, fcw_s[4 * m + 3], a);
            }
            out[(t0 + i) * BB + b] = a + fcb + xsh[i];
        }
    };

    const _Float16* rd_p;  // h(t-1) slice base; advanced 4 rows at a time
    _Float16*       wr_p;  // h(t) cell slot base

    auto step = [&](float gx, const int ofs) {   // ofs: constant element offset
        const uint4* hrow = (const uint4*)(rd_p + ofs);
        uint4 u0 = hrow[0], u1 = hrow[1], u2 = hrow[2];
        f16x2 h2[12] = {
            __builtin_bit_cast(f16x2, u0.x), __builtin_bit_cast(f16x2, u0.y),
            __builtin_bit_cast(f16x2, u0.z), __builtin_bit_cast(f16x2, u0.w),
            __builtin_bit_cast(f16x2, u1.x), __builtin_bit_cast(f16x2, u1.y),
            __builtin_bit_cast(f16x2, u1.z), __builtin_bit_cast(f16x2, u1.w),
            __builtin_bit_cast(f16x2, u2.x), __builtin_bit_cast(f16x2, u2.y),
            __builtin_bit_cast(f16x2, u2.z), __builtin_bit_cast(f16x2, u2.w)};

        float acc[4];
        acc[0] = gx;       // own gate's x+bias term rides slot 0 (lane-local)
        acc[1] = 0.0f;
        acc[2] = 0.0f;
        acc[3] = 0.0f;
#pragma unroll
        for (int d = 0; d < 4; ++d) {
            float e = acc[d];
#pragma unroll
            for (int m = 0; m < 12; ++m) e = dot2_f16(W[d][m], h2[m], e);
            acc[d] = e;
        }
        // XOR butterfly: lane s ends with gate s's full pre-scaled sum.
        const float b0  = dpp_add2<DPP_XOR1>(acc[0], acc[1]);
        const float b1  = dpp_add2<DPP_XOR1>(acc[2], acc[3]);
        const float pre = dpp_add2<DPP_XOR2>(b0, b1);

        const float act =
            fmaf(__builtin_amdgcn_rcpf(1.0f + __builtin_amdgcn_exp2f(pre)),
                 a_mul, a_add);
        const float fv = dpp_bcast<DPP_B1>(act);
        const float gv = dpp_bcast<DPP_B2>(act);   // already -2k-scaled
        const float ov = dpp_bcast<DPP_B3>(act);
        c = fmaf(fv, c, act * gv);                 // stays in scaled domain
        // tanh(c_true) = 2*rcp(1+2^c') - 1 ; h = o*tanh = fma(2o, r, -o)
        const float r  = __builtin_amdgcn_rcpf(1.0f + __builtin_amdgcn_exp2f(c));
        const float o2 = ov + ov;                  // off-chain
        const float h  = fmaf(o2, r, -ov);
        if (s == 0) *(wr_p + ofs) = (_Float16)h;
        __syncthreads();
    };

    for (int w = 0; w < TT / NS; ++w) {
        const int t0 = w * NS;
        if (w == 0) {
            if (stid < 48) ((uint32_t*)histh)[stid] = 0u;  // row 0 = h(-1) = 0
        } else {
            flush(t0 - NS);                                // old xs + rows 1..NS
            if (stid < 48)                                 // row NS -> row 0
                ((uint32_t*)histh)[stid] =
                    ((const uint32_t*)(histh + NS * ROWP))[stid];
        }
        __syncthreads();
        for (int i = stid; i < NS; i += THH) xsh[i] = x[(t0 + i) * BB + b];
        __syncthreads();

        rd_p = histh + 24 * s;
        wr_p = histh + ROWP + j;
        for (int tt = 0; tt < NS; tt += 4) {
            const float4 xq = *(const float4*)(xsh + tt);  // broadcast
            const float gx0 = fmaf(xq.x, wih2, bias2);     // off-chain
            const float gx1 = fmaf(xq.y, wih2, bias2);
            const float gx2 = fmaf(xq.z, wih2, bias2);
            const float gx3 = fmaf(xq.w, wih2, bias2);
            step(gx0, 0 * ROWP);
            step(gx1, 1 * ROWP);
            step(gx2, 2 * ROWP);
            step(gx3, 3 * ROWP);
            rd_p += 4 * ROWP;
            wr_p += 4 * ROWP;
        }
    }
    flush(TT - NS);   // last window (loop ended with a barrier)
}

extern "C" void kernel_launch(void* const* d_in, const int* in_sizes, int n_in,
                              void* d_out, int out_size, void* d_ws, size_t ws_size,
                              hipStream_t stream) {
    const float* x    = (const float*)d_in[0];
    const float* w_ih = (const float*)d_in[1];
    const float* w_hh = (const float*)d_in[2];
    const float* b_ih = (const float*)d_in[3];
    const float* b_hh = (const float*)d_in[4];
    const float* fc_w = (const float*)d_in[5];
    const float* fc_b = (const float*)d_in[6];
    float* out = (float*)d_out;

    lstm_kernel<<<dim3(NB), dim3(TH), 0, stream>>>(x, w_ih, w_hh, b_ih, b_hh,
                                                   fc_w, fc_b, out);
}

// Round 3
// 7108.050 us; speedup vs baseline: 1.1657x; 1.1657x over previous
//
#include <hip/hip_runtime.h>

// LSTM T=16384, B=32, H=96. 32 blocks x 384 thr (6 waves). History:
// R15 = 6240us (chain-fold), R16 (2 batches/block) = 8286us FAILED -- shared
// barrier phase-locks both recurrences (stalls align: max not sum) while dot
// issue stacks 3 waves/SIMD. Model: step ~460cy @ ~1.2GHz = 292cy issue on
// critical 2-wave SIMD + ~170cy roundtrip/tail latency.
// R17 (this): move the 36864 MAC/step onto the MATRIX pipe.
//   - Per wave: 16 cells x 4 gates = 64 rows = 4 tiles of mfma_f32_16x16x32_f16
//     x 3 K-tiles = 12 MFMA (issue ~24cy, pipe concurrent with VALU) replacing
//     48 v_dot2 (192cy on critical SIMD) + butterfly.
//   - B operand = h(t-1) replicated across all 16 cols (lane-uniform-ish
//     ds_read_b128 x3). Replication makes B's col mapping irrelevant, and any
//     consistent A/B k-permutation cancels in the contraction.
//   - C layout (HW-verified): col=lane&15, row=4*(lane>>4)+reg. With B
//     replicated, each lane holds ALL FOUR gate pre-acts of cell
//     16*wv + 4*(lane>>4) + reg -- tail is fully lane-local: 3-cndmask select
//     (reg = lane&3), no DPP anywhere, 4x redundant c/h per cell, lanes
//     (lane&15)<4 write h.
//   - e_k prefold into A/wih/bias, scaled-domain c' = -2k*c, exp2-folded
//     activations (i,f,o: act = rcp directly, no fma) -- all kept from R15.
// LDS layout, 513-row slot-shifted history, float4 x broadcast, one
// barrier/step, bulk fc flush: unchanged from R15.

constexpr int HH   = 96;
constexpr int BB   = 32;
constexpr int TT   = 16384;
constexpr int TH   = 384;   // 6 waves
constexpr int NS   = 512;   // h history window
constexpr int ROWP = 104;   // halves per hist row: 208 B, 16B-aligned

typedef _Float16 f16x8 __attribute__((ext_vector_type(8)));
typedef _Float16 f16x2 __attribute__((ext_vector_type(2)));
typedef float    f32x4 __attribute__((ext_vector_type(4)));

#define LOG2E 1.44269504f

__attribute__((amdgpu_flat_work_group_size(TH, TH)))
__global__ void lstm_kernel(const float* __restrict__ x,
                            const float* __restrict__ w_ih,
                            const float* __restrict__ w_hh,
                            const float* __restrict__ b_ih,
                            const float* __restrict__ b_hh,
                            const float* __restrict__ fc_w,
                            const float* __restrict__ fc_b,
                            float* __restrict__ out) {
    __shared__ __align__(16) _Float16 hist[(NS + 1) * ROWP];  // ~104 KB
    __shared__ __align__(16) float xs[NS];                    // 2 KB x window
    __shared__ float fcw_s[HH];

    const int tid = threadIdx.x;
    const int b   = blockIdx.x;
    const int wv  = tid >> 6;   // wave 0..5, owns cells [16wv, 16wv+16)
    const int l   = tid & 63;
    const int h16 = l >> 4;     // k-group / row-subgroup 0..3
    const int rIn = l & 15;     // A-row within tile
    const int r3  = l & 3;      // C-reg select
    const int j   = 16 * wv + 4 * h16 + r3;  // this lane's cell 0..95

    // A fragments, e_k-prescaled: A[g][kt] holds row (g*96 + 16wv + rIn),
    // k = kt*32 + 8*h16 + e  (lane = row + 16*kgroup convention).
    f16x8 A[4][3];
#pragma unroll
    for (int g = 0; g < 4; ++g) {
        const float ek = (g == 2) ? (-2.0f * LOG2E) : (-LOG2E);
        const float* wrow = w_hh + (g * HH + 16 * wv + rIn) * HH;
#pragma unroll
        for (int kt = 0; kt < 3; ++kt) {
            const float* wr = wrow + kt * 32 + 8 * h16;
            f16x8 v;
#pragma unroll
            for (int e = 0; e < 8; ++e) v[e] = (_Float16)(wr[e] * ek);
            A[g][kt] = v;
        }
    }
#pragma unroll
    for (int g = 0; g < 4; ++g)
#pragma unroll
        for (int kt = 0; kt < 3; ++kt) asm volatile("" : "+v"(A[g][kt]));

    float wih2[4], bias2[4];
#pragma unroll
    for (int g = 0; g < 4; ++g) {
        const float ek = (g == 2) ? (-2.0f * LOG2E) : (-LOG2E);
        wih2[g]  = w_ih[g * HH + j] * ek;
        bias2[g] = (b_ih[g * HH + j] + b_hh[g * HH + j]) * ek;
    }
    const bool s1 = (r3 == 1), s2 = (r3 == 2), s3 = (r3 == 3);

    const float fcb = fc_b[0];
    float c = 0.0f;   // scaled domain: c' = -2*log2e * c_true

    for (int i = tid; i < HH; i += TH) fcw_s[i] = fc_w[i];

    // Bulk fc projection for window [t0, t0+NS): h(t0+i) is in hist row i+1.
    auto flush = [&](int t0) {
        for (int i = tid; i < NS; i += TH) {
            const uint2* hr = (const uint2*)(hist + (i + 1) * ROWP);
            float a = 0.0f;
#pragma unroll
            for (int m = 0; m < 24; ++m) {
                uint2 u = hr[m];
                f16x2 p0 = __builtin_bit_cast(f16x2, u.x);
                f16x2 p1 = __builtin_bit_cast(f16x2, u.y);
                a = fmaf((float)p0.x, fcw_s[4 * m + 0], a);
                a = fmaf((float)p0.y, fcw_s[4 * m + 1], a);
                a = fmaf((float)p1.x, fcw_s[4 * m + 2], a);
                a = fmaf((float)p1.y, fcw_s[4 * m + 3], a);
            }
            out[(t0 + i) * BB + b] = a + fcb + xs[i];
        }
    };

    const _Float16* rd_p;  // h(t-1) B-frag base (lane k-offset); +4 rows/block
    _Float16*       wr_p;  // h(t) cell slot base

    auto step = [&](float xv, const int ofs) {   // ofs: constant element offset
        const uint4* p = (const uint4*)(rd_p + ofs);
        uint4 u0 = p[0], u1 = p[4], u2 = p[8];   // kt strides: 32 halves = 64B
        const f16x8 b0 = __builtin_bit_cast(f16x8, u0);
        const f16x8 b1 = __builtin_bit_cast(f16x8, u1);
        const f16x8 b2 = __builtin_bit_cast(f16x8, u2);

        f32x4 acc[4];
#pragma unroll
        for (int g = 0; g < 4; ++g) {
            f32x4 z = {0.0f, 0.0f, 0.0f, 0.0f};
            z = __builtin_amdgcn_mfma_f32_16x16x32_f16(A[g][0], b0, z, 0, 0, 0);
            z = __builtin_amdgcn_mfma_f32_16x16x32_f16(A[g][1], b1, z, 0, 0, 0);
            z = __builtin_amdgcn_mfma_f32_16x16x32_f16(A[g][2], b2, z, 0, 0, 0);
            acc[g] = z;
        }
        // Lane-local gather: reg r3 of each gate-tile is this lane's cell.
        float pre[4];
#pragma unroll
        for (int g = 0; g < 4; ++g) {
            float v = s1 ? acc[g][1] : acc[g][0];
            v = s2 ? acc[g][2] : v;
            v = s3 ? acc[g][3] : v;
            pre[g] = v + fmaf(xv, wih2[g], bias2[g]);  // gx off-chain
        }
        const float ri = __builtin_amdgcn_rcpf(1.0f + __builtin_amdgcn_exp2f(pre[0]));
        const float rf = __builtin_amdgcn_rcpf(1.0f + __builtin_amdgcn_exp2f(pre[1]));
        const float gp = fmaf(__builtin_amdgcn_rcpf(1.0f + __builtin_amdgcn_exp2f(pre[2])),
                              -4.0f * LOG2E, 2.0f * LOG2E);
        const float ro = __builtin_amdgcn_rcpf(1.0f + __builtin_amdgcn_exp2f(pre[3]));
        c = fmaf(rf, c, ri * gp);                 // scaled domain
        const float rt = __builtin_amdgcn_rcpf(1.0f + __builtin_amdgcn_exp2f(c));
        const float h  = fmaf(ro + ro, rt, -ro);  // o*tanh(c_true)
        if (rIn < 4) *(wr_p + ofs) = (_Float16)h;
        __syncthreads();
    };

    for (int w = 0; w < TT / NS; ++w) {
        const int t0 = w * NS;
        if (w == 0) {
            if (tid < 48) ((uint32_t*)hist)[tid] = 0u;  // row 0 = h(-1) = 0
        } else {
            flush(t0 - NS);                              // old xs + rows 1..512
            if (tid < 48)                                // row 512 -> row 0
                ((uint32_t*)hist)[tid] = ((const uint32_t*)(hist + NS * ROWP))[tid];
        }
        __syncthreads();
        for (int i = tid; i < NS; i += TH) xs[i] = x[(t0 + i) * BB + b];
        __syncthreads();

        rd_p = hist + 8 * h16;
        wr_p = hist + ROWP + j;
        for (int tt = 0; tt < NS; tt += 4) {
            const float4 xq = *(const float4*)(xs + tt);  // broadcast
            step(xq.x, 0 * ROWP);
            step(xq.y, 1 * ROWP);
            step(xq.z, 2 * ROWP);
            step(xq.w, 3 * ROWP);
            rd_p += 4 * ROWP;
            wr_p += 4 * ROWP;
        }
    }
    flush(TT - NS);   // last window (loop ended with a barrier)
}

extern "C" void kernel_launch(void* const* d_in, const int* in_sizes, int n_in,
                              void* d_out, int out_size, void* d_ws, size_t ws_size,
                              hipStream_t stream) {
    const float* x    = (const float*)d_in[0];
    const float* w_ih = (const float*)d_in[1];
    const float* w_hh = (const float*)d_in[2];
    const float* b_ih = (const float*)d_in[3];
    const float* b_hh = (const float*)d_in[4];
    const float* fc_w = (const float*)d_in[5];
    const float* fc_b = (const float*)d_in[6];
    float* out = (float*)d_out;

    lstm_kernel<<<dim3(BB), dim3(TH), 0, stream>>>(x, w_ih, w_hh, b_ih, b_hh,
                                                   fc_w, fc_b, out);
}

// Round 4
// 5142.442 us; speedup vs baseline: 1.6112x; 1.3822x over previous
//
#include <hip/hip_runtime.h>

// LSTM T=16384, B=32, H=96. 32 blocks x 384 thr (6 waves).
// R15 = 6240us (dot2 + quad butterfly). R17 (MFMA, outputs in ROW dim) =
// 7108us: correct (verified A-row=lane&15 + k-map consistency on HW) but the
// tail quadrupled (every lane did all 4 gates: 4 exp2/rcp + 12 cndmask on the
// serial chain) and per-gate 3-MFMA accumulate chains sat behind the ds_read.
// R18 (this): SWAPPED operands -- A = h(t-1) replicated across the 16 rows
// (same broadcast ds_read_b128 x3 as R17), B = weights with outputs in the
// COLUMN dimension. We choose the col->(cell,gate) map: tile t, col c ->
// cell 4t+(c>>2), gate c&3. Lane l=16*h16+rIn then extracts acc[h16][0]
// (reg index compile-time, 3-cndmask tile select), and the DPP quad
// rIn&3=0..3 holds one cell's 4 gates -> R15's cheap tail returns verbatim
// (1 exp2+rcp per lane, B1/B2/B3 broadcasts, c-update, tanh, s==0 writes).
// Per-wave issue ~76 -> ~43 instr, 12 of them MFMA on the separate matrix
// pipe, interleaved kt-outer so the 4 independent tile-chains hide each
// other's latency. e_k prefold, scaled-domain c, gx off-chain: kept.
// Only new layout bet: B-col = lane&15 (dual of the R17-verified A-row map).

constexpr int HH   = 96;
constexpr int BB   = 32;
constexpr int TT   = 16384;
constexpr int TH   = 384;   // 6 waves
constexpr int NS   = 512;   // h history window
constexpr int ROWP = 104;   // halves per hist row: 208 B, 16B-aligned

typedef _Float16 f16x8 __attribute__((ext_vector_type(8)));
typedef _Float16 f16x2 __attribute__((ext_vector_type(2)));
typedef float    f32x4 __attribute__((ext_vector_type(4)));

template <int CTRL>
__device__ __forceinline__ float dpp_bcast(float v) {
    int r = __builtin_amdgcn_mov_dpp(__builtin_bit_cast(int, v), CTRL, 0xF, 0xF, true);
    return __builtin_bit_cast(float, r);
}
constexpr int DPP_B1 = 0x55;
constexpr int DPP_B2 = 0xAA;
constexpr int DPP_B3 = 0xFF;

#define LOG2E 1.44269504f

__attribute__((amdgpu_flat_work_group_size(TH, TH)))
__global__ void lstm_kernel(const float* __restrict__ x,
                            const float* __restrict__ w_ih,
                            const float* __restrict__ w_hh,
                            const float* __restrict__ b_ih,
                            const float* __restrict__ b_hh,
                            const float* __restrict__ fc_w,
                            const float* __restrict__ fc_b,
                            float* __restrict__ out) {
    __shared__ __align__(16) _Float16 hist[(NS + 1) * ROWP];  // ~104 KB
    __shared__ __align__(16) float xs[NS];                    // 2 KB x window
    __shared__ float fcw_s[HH];

    const int tid = threadIdx.x;
    const int b   = blockIdx.x;
    const int wv  = tid >> 6;   // wave 0..5, owns cells [16wv, 16wv+16)
    const int l   = tid & 63;
    const int h16 = l >> 4;     // k-group; also this lane's TILE index
    const int rIn = l & 15;     // col within tile
    const int s   = rIn & 3;    // gate 0..3 (quad lane)
    const int q   = rIn >> 2;   // cell-sub within tile
    const int j   = 16 * wv + 4 * h16 + q;  // this lane's cell 0..95

    // B fragments (weights), e_k-prescaled. Tile t col rIn holds W row
    // (gate s, cell 16wv+4t+q); lane's k slice = kt*32 + 8*h16 + e.
    const float ek_s = (s == 2) ? (-2.0f * LOG2E) : (-LOG2E);
    f16x8 Bw[4][3];
#pragma unroll
    for (int t = 0; t < 4; ++t) {
        const float* wrow = w_hh + (s * HH + 16 * wv + 4 * t + q) * HH;
#pragma unroll
        for (int kt = 0; kt < 3; ++kt) {
            const float* wr = wrow + kt * 32 + 8 * h16;
            f16x8 v;
#pragma unroll
            for (int e = 0; e < 8; ++e) v[e] = (_Float16)(wr[e] * ek_s);
            Bw[t][kt] = v;
        }
    }
#pragma unroll
    for (int t = 0; t < 4; ++t)
#pragma unroll
        for (int kt = 0; kt < 3; ++kt) asm volatile("" : "+v"(Bw[t][kt]));

    const float wih2  = w_ih[s * HH + j] * ek_s;
    const float bias2 = (b_ih[s * HH + j] + b_hh[s * HH + j]) * ek_s;
    const float a_mul = (s == 2) ? (-4.0f * LOG2E) : 1.0f;
    const float a_add = (s == 2) ? (2.0f * LOG2E) : 0.0f;
    const bool  t1 = (h16 == 1), t2 = (h16 == 2), t3 = (h16 == 3);

    const float fcb = fc_b[0];
    float c = 0.0f;   // scaled domain: c' = -2*log2e * c_true

    for (int i = tid; i < HH; i += TH) fcw_s[i] = fc_w[i];

    // Bulk fc projection for window [t0, t0+NS): h(t0+i) is in hist row i+1.
    auto flush = [&](int t0) {
        for (int i = tid; i < NS; i += TH) {
            const uint2* hr = (const uint2*)(hist + (i + 1) * ROWP);
            float a = 0.0f;
#pragma unroll
            for (int m = 0; m < 24; ++m) {
                uint2 u = hr[m];
                f16x2 p0 = __builtin_bit_cast(f16x2, u.x);
                f16x2 p1 = __builtin_bit_cast(f16x2, u.y);
                a = fmaf((float)p0.x, fcw_s[4 * m + 0], a);
                a = fmaf((float)p0.y, fcw_s[4 * m + 1], a);
                a = fmaf((float)p1.x, fcw_s[4 * m + 2], a);
                a = fmaf((float)p1.y, fcw_s[4 * m + 3], a);
            }
            out[(t0 + i) * BB + b] = a + fcb + xs[i];
        }
    };

    const _Float16* rd_p;  // h(t-1) k-slice base (8*h16); +4 rows per block
    _Float16*       wr_p;  // h(t) cell slot base

    auto step = [&](float gx, const int ofs) {   // ofs: constant element offset
        const uint4* p = (const uint4*)(rd_p + ofs);
        uint4 u0 = p[0], u1 = p[4], u2 = p[8];   // kt stride: 32 halves = 64B
        const f16x8 a0 = __builtin_bit_cast(f16x8, u0);
        const f16x8 a1 = __builtin_bit_cast(f16x8, u1);
        const f16x8 a2 = __builtin_bit_cast(f16x8, u2);

        f32x4 acc[4] = {{0.f, 0.f, 0.f, 0.f}, {0.f, 0.f, 0.f, 0.f},
                        {0.f, 0.f, 0.f, 0.f}, {0.f, 0.f, 0.f, 0.f}};
        // kt-outer: 4 independent tile-chains interleave, hiding MFMA latency.
#pragma unroll
        for (int t = 0; t < 4; ++t)
            acc[t] = __builtin_amdgcn_mfma_f32_16x16x32_f16(a0, Bw[t][0], acc[t], 0, 0, 0);
#pragma unroll
        for (int t = 0; t < 4; ++t)
            acc[t] = __builtin_amdgcn_mfma_f32_16x16x32_f16(a1, Bw[t][1], acc[t], 0, 0, 0);
#pragma unroll
        for (int t = 0; t < 4; ++t)
            acc[t] = __builtin_amdgcn_mfma_f32_16x16x32_f16(a2, Bw[t][2], acc[t], 0, 0, 0);

        // Rows are replicas -> reg 0 always; 3-cndmask tile select by h16.
        float v = t1 ? acc[1][0] : acc[0][0];
        v       = t2 ? acc[2][0] : v;
        v       = t3 ? acc[3][0] : v;

        const float pre = v + gx;
        const float act =
            fmaf(__builtin_amdgcn_rcpf(1.0f + __builtin_amdgcn_exp2f(pre)),
                 a_mul, a_add);
        const float fv = dpp_bcast<DPP_B1>(act);
        const float gv = dpp_bcast<DPP_B2>(act);   // already -2k-scaled
        const float ov = dpp_bcast<DPP_B3>(act);
        c = fmaf(fv, c, act * gv);                 // scaled domain
        const float rt = __builtin_amdgcn_rcpf(1.0f + __builtin_amdgcn_exp2f(c));
        const float h  = fmaf(ov + ov, rt, -ov);   // o * tanh(c_true)
        if (s == 0) *(wr_p + ofs) = (_Float16)h;
        __syncthreads();
    };

    for (int w = 0; w < TT / NS; ++w) {
        const int t0 = w * NS;
        if (w == 0) {
            if (tid < 48) ((uint32_t*)hist)[tid] = 0u;  // row 0 = h(-1) = 0
        } else {
            flush(t0 - NS);                              // old xs + rows 1..512
            if (tid < 48)                                // row 512 -> row 0
                ((uint32_t*)hist)[tid] = ((const uint32_t*)(hist + NS * ROWP))[tid];
        }
        __syncthreads();
        for (int i = tid; i < NS; i += TH) xs[i] = x[(t0 + i) * BB + b];
        __syncthreads();

        rd_p = hist + 8 * h16;
        wr_p = hist + ROWP + j;
        for (int tt = 0; tt < NS; tt += 4) {
            const float4 xq = *(const float4*)(xs + tt);  // broadcast
            const float gx0 = fmaf(xq.x, wih2, bias2);    // off-chain
            const float gx1 = fmaf(xq.y, wih2, bias2);
            const float gx2 = fmaf(xq.z, wih2, bias2);
            const float gx3 = fmaf(xq.w, wih2, bias2);
            step(gx0, 0 * ROWP);
            step(gx1, 1 * ROWP);
            step(gx2, 2 * ROWP);
            step(gx3, 3 * ROWP);
            rd_p += 4 * ROWP;
            wr_p += 4 * ROWP;
        }
    }
    flush(TT - NS);   // last window (loop ended with a barrier)
}

extern "C" void kernel_launch(void* const* d_in, const int* in_sizes, int n_in,
                              void* d_out, int out_size, void* d_ws, size_t ws_size,
                              hipStream_t stream) {
    const float* x    = (const float*)d_in[0];
    const float* w_ih = (const float*)d_in[1];
    const float* w_hh = (const float*)d_in[2];
    const float* b_ih = (const float*)d_in[3];
    const float* b_hh = (const float*)d_in[4];
    const float* fc_w = (const float*)d_in[5];
    const float* fc_b = (const float*)d_in[6];
    float* out = (float*)d_out;

    lstm_kernel<<<dim3(BB), dim3(TH), 0, stream>>>(x, w_ih, w_hh, b_ih, b_hh,
                                                   fc_w, fc_b, out);
}